// Round 3
// baseline (150.412 us; speedup 1.0000x reference)
//
#include <hip/hip_runtime.h>

#define C_ 64
#define CI_ 32
#define N_ 4096
#define LOG2E 1.4426950408889634f

typedef __attribute__((ext_vector_type(8))) short bf16x8;
typedef __attribute__((ext_vector_type(4))) float f32x4;

__device__ __forceinline__ unsigned short f2bf_rne(float f) {
  unsigned u = __builtin_bit_cast(unsigned, f);
  unsigned r = (u + 0x7FFFu + ((u >> 16) & 1u)) >> 16;
  return (unsigned short)r;
}
__device__ __forceinline__ unsigned pack_bf2(float lo, float hi) {
  unsigned a = (__builtin_bit_cast(unsigned, lo) + 0x8000u) >> 16;
  unsigned b = (__builtin_bit_cast(unsigned, hi) + 0x8000u) & 0xFFFF0000u;
  return a | b;
}

// ---------------------------------------------------------------------------
// K1: projections. Grid 192 = (proj x b x 16 n-tiles of 256). Block 256 thr,
// wave = channel octet; thread = 4 consecutive n via float4 loads.
// Weights are wave-uniform -> SGPR. theta pre-scaled by log2(e).
// ---------------------------------------------------------------------------
__global__ __launch_bounds__(256) void k1_proj(
    const float* __restrict__ supp, const float* __restrict__ ref,
    const float* __restrict__ tw, const float* __restrict__ tb,
    const float* __restrict__ pw, const float* __restrict__ pb,
    const float* __restrict__ gw, const float* __restrict__ gb,
    unsigned short* __restrict__ theta, unsigned short* __restrict__ phi,
    float* __restrict__ gt)
{
  const int proj = blockIdx.x >> 6;
  const int rr = blockIdx.x & 63;
  const int b = rr >> 4;
  const int n0 = (rr & 15) << 8;
  const int o = __builtin_amdgcn_readfirstlane(threadIdx.x >> 6);
  const int lane = threadIdx.x & 63;
  const int nb = n0 + lane * 4;

  const float *W, *bias, *src;
  if (proj == 0)      { W = tw; bias = tb; src = supp; }
  else if (proj == 1) { W = pw; bias = pb; src = ref; }
  else                { W = gw; bias = gb; src = ref; }

  const float* x = src + (size_t)b * (C_ * N_) + nb;
  const float* Wo = W + o * 8 * C_;
  float4 acc[8];
#pragma unroll
  for (int k = 0; k < 8; k++) {
    float bv = bias[o * 8 + k];
    acc[k].x = bv; acc[k].y = bv; acc[k].z = bv; acc[k].w = bv;
  }
#pragma unroll 4
  for (int c = 0; c < C_; c++) {
    float4 v = *(const float4*)(x + (size_t)c * N_);
#pragma unroll
    for (int k = 0; k < 8; k++) {
      float wv = Wo[k * C_ + c];
      acc[k].x = fmaf(wv, v.x, acc[k].x);
      acc[k].y = fmaf(wv, v.y, acc[k].y);
      acc[k].z = fmaf(wv, v.z, acc[k].z);
      acc[k].w = fmaf(wv, v.w, acc[k].w);
    }
  }

  const int p0 = b * N_ + nb;
  if (proj == 0) {
#pragma unroll
    for (int j = 0; j < 4; j++) {
      float av[8];
#pragma unroll
      for (int k = 0; k < 8; k++) av[k] = (&acc[k].x)[j] * LOG2E;
      unsigned pk[4];
#pragma unroll
      for (int k = 0; k < 4; k++)
        pk[k] = (unsigned)f2bf_rne(av[2 * k]) | ((unsigned)f2bf_rne(av[2 * k + 1]) << 16);
      *(uint4*)(theta + (((size_t)p0 + j) << 5) + o * 8) = *(uint4*)pk;
    }
  } else if (proj == 1) {
#pragma unroll
    for (int j = 0; j < 4; j++) {
      unsigned pk[4];
#pragma unroll
      for (int k = 0; k < 4; k++)
        pk[k] = (unsigned)f2bf_rne((&acc[2 * k].x)[j]) |
                ((unsigned)f2bf_rne((&acc[2 * k + 1].x)[j]) << 16);
      *(uint4*)(phi + (((size_t)p0 + j) << 5) + o * 8) = *(uint4*)pk;
    }
  } else {
#pragma unroll
    for (int k = 0; k < 8; k++)
      *(float4*)(gt + ((size_t)b * CI_ + o * 8 + k) * N_ + nb) = acc[k];
  }
}

// ---------------------------------------------------------------------------
// K2: den[m] = sum_n exp2(f'); gy2i[b][i][sigma(m)] = bf16(gt/den).
// Grid 256 = (b x 64 m-tiles of 64). Block 1024 thr; wave = 256-n slice.
// Each wave holds 4 persistent phi B-frags (whole 64-m tile): per A-load it
// does 4 MFMAs + 16 exps (theta read exactly once per block, no redundancy).
// ---------------------------------------------------------------------------
__global__ __launch_bounds__(1024) void k2_den(
    const unsigned short* __restrict__ theta, const unsigned short* __restrict__ phi,
    const float* __restrict__ gt, unsigned short* __restrict__ gy2i)
{
  const int tid = threadIdx.x;
  const int wave = tid >> 6;
  const int lane = tid & 63;
  const int b = blockIdx.x >> 6;
  const int mbase = (blockIdx.x & 63) << 6;
  const int row16 = lane & 15;
  const int quad = lane >> 4;

  bf16x8 bf[4];
#pragma unroll
  for (int f = 0; f < 4; f++)
    bf[f] = *(const bf16x8*)(phi +
        (((size_t)b * N_ + mbase + f * 16 + row16) << 5) + (quad << 3));

  const unsigned short* abase = theta +
      (((size_t)b * N_ + wave * 256 + row16) << 5) + (quad << 3);

  f32x4 zero = {0.f, 0.f, 0.f, 0.f};
  float dd[16];
#pragma unroll
  for (int k = 0; k < 16; k++) dd[k] = 0.f;

  bf16x8 a0 = *(const bf16x8*)abase;
#pragma unroll 2
  for (int it = 0; it < 16; it++) {
    int itn = it + 1 <= 15 ? it + 1 : 15;
    bf16x8 an = *(const bf16x8*)(abase + ((size_t)itn << 9));
#pragma unroll
    for (int f = 0; f < 4; f++) {
      f32x4 ff = __builtin_amdgcn_mfma_f32_16x16x32_bf16(a0, bf[f], zero, 0, 0, 0);
#pragma unroll
      for (int r = 0; r < 4; r++) dd[f * 4 + r] += __builtin_amdgcn_exp2f(ff[r]);
    }
    a0 = an;
  }

  __shared__ float denp[16][64];
#pragma unroll
  for (int f = 0; f < 4; f++) {
    float v = (dd[f * 4] + dd[f * 4 + 1]) + (dd[f * 4 + 2] + dd[f * 4 + 3]);
    v += __shfl_xor(v, 16);
    v += __shfl_xor(v, 32);
    if (lane < 16) denp[wave][f * 16 + lane] = v;
  }
  __syncthreads();

  for (int e = tid; e < CI_ * 64; e += 1024) {
    int i = e >> 6;
    int ml = e & 63;
    float den = 0.f;
#pragma unroll
    for (int w = 0; w < 16; w++) den += denp[w][ml];
    int within = ml & 31;
    int pos = ((within & 15) << 1) | (within >> 4);
    size_t rowb = ((size_t)b * CI_ + i) * N_ + mbase;
    gy2i[rowb + (ml & 32) + pos] = f2bf_rne(gt[rowb + ml] / den);
  }
}

// ---------------------------------------------------------------------------
// K3: x1[n][i] partial over an m-half. Grid 256 = (b x 32 n-tiles of 128 x
// 2 m-halves of 2048). Block 512 thr = 8 waves, one 16-n subtile each; all
// waves share each 32-m phi/gy2 tile (L1 broadcast). P round-trips per-wave
// LDS with 96B row stride (bank-balanced b128 reads). Acc = D[n][i], 2 frags.
// 24KB LDS -> 4 blocks/CU co-resident.
// ---------------------------------------------------------------------------
__global__ __launch_bounds__(512, 6) void k3_attn(
    const unsigned short* __restrict__ theta, const unsigned short* __restrict__ phi,
    const unsigned short* __restrict__ gy2i, float* __restrict__ x1p)
{
  const int tid = threadIdx.x;
  const int w = tid >> 6;
  const int lane = tid & 63;
  const int b = blockIdx.x >> 6;
  const int r2 = blockIdx.x & 63;
  const int n0 = (r2 >> 1) << 7;
  const int mbase = (r2 & 1) << 11;
  const int row16 = lane & 15;
  const int quad = lane >> 4;

  __shared__ unsigned Pbuf[8][2][16 * 24];   // dwords; row stride 24 dw = 96B

  bf16x8 afrag = *(const bf16x8*)(theta +
      (((size_t)b * N_ + n0 + w * 16 + row16) << 5) + (quad << 3));

  const unsigned short* pbp = phi +
      (((size_t)b * N_ + mbase + row16) << 5) + (quad << 3);
  const unsigned short* gpp = gy2i +
      ((size_t)b * CI_ + row16) * N_ + mbase + (quad << 3);

  unsigned* wr0 = &Pbuf[w][0][quad * 4 * 24 + row16];
  unsigned* wr1 = &Pbuf[w][1][quad * 4 * 24 + row16];
  const unsigned* rd0 = &Pbuf[w][0][row16 * 24 + quad * 4];
  const unsigned* rd1 = &Pbuf[w][1][row16 * 24 + quad * 4];

  f32x4 zero = {0.f, 0.f, 0.f, 0.f};
  f32x4 x1a = zero, x1b = zero;

  // prologue (it = 0)
  bf16x8 cb0 = *(const bf16x8*)pbp;
  bf16x8 cb1 = *(const bf16x8*)(pbp + 512);
  f32x4 f0 = __builtin_amdgcn_mfma_f32_16x16x32_bf16(afrag, cb0, zero, 0, 0, 0);
  f32x4 f1 = __builtin_amdgcn_mfma_f32_16x16x32_bf16(afrag, cb1, zero, 0, 0, 0);
  bf16x8 nb0 = *(const bf16x8*)(pbp + 1024);
  bf16x8 nb1 = *(const bf16x8*)(pbp + 1536);
  bf16x8 cg0 = *(const bf16x8*)gpp;
  bf16x8 cg1 = *(const bf16x8*)(gpp + (size_t)16 * N_);
#pragma unroll
  for (int r = 0; r < 4; r++)
    wr0[r * 24] = pack_bf2(__builtin_amdgcn_exp2f(f0[r]), __builtin_amdgcn_exp2f(f1[r]));

  for (int it = 1; it < 64; it++) {
    bf16x8 pa = *(const bf16x8*)((it & 1) ? rd0 : rd1);
    f0 = __builtin_amdgcn_mfma_f32_16x16x32_bf16(afrag, nb0, zero, 0, 0, 0);
    f1 = __builtin_amdgcn_mfma_f32_16x16x32_bf16(afrag, nb1, zero, 0, 0, 0);
    int itn = it + 1 <= 63 ? it + 1 : 63;
    nb0 = *(const bf16x8*)(pbp + itn * 1024);
    nb1 = *(const bf16x8*)(pbp + itn * 1024 + 512);
    unsigned* wr = (it & 1) ? wr1 : wr0;
#pragma unroll
    for (int r = 0; r < 4; r++)
      wr[r * 24] = pack_bf2(__builtin_amdgcn_exp2f(f0[r]), __builtin_amdgcn_exp2f(f1[r]));
    x1a = __builtin_amdgcn_mfma_f32_16x16x32_bf16(pa, cg0, x1a, 0, 0, 0);
    x1b = __builtin_amdgcn_mfma_f32_16x16x32_bf16(pa, cg1, x1b, 0, 0, 0);
    cg0 = *(const bf16x8*)(gpp + it * 32);
    cg1 = *(const bf16x8*)(gpp + (size_t)16 * N_ + it * 32);
  }
  {
    bf16x8 pa = *(const bf16x8*)rd1;   // it=63 wrote buf 1
    x1a = __builtin_amdgcn_mfma_f32_16x16x32_bf16(pa, cg0, x1a, 0, 0, 0);
    x1b = __builtin_amdgcn_mfma_f32_16x16x32_bf16(pa, cg1, x1b, 0, 0, 0);
  }

  // store partial: x1p[b][mh][n][i], D-layout: col=i'=lane&15, row=quad*4+r
  const int mh = r2 & 1;
  size_t base = (((size_t)(b * 2 + mh) * N_) + n0 + w * 16 + quad * 4) << 5;
#pragma unroll
  for (int r = 0; r < 4; r++) {
    x1p[base + ((size_t)r << 5) + row16] = x1a[r];
    x1p[base + ((size_t)r << 5) + row16 + 16] = x1b[r];
  }
}

// ---------------------------------------------------------------------------
// K4: x1 = sum of 2 m-half partials; out = supp + ww.x1 + wb.
// Grid 256 = (b x 64 n-tiles of 64). Block 256 thr; thread = (c0, 4 n) x 4 c.
// ---------------------------------------------------------------------------
__global__ __launch_bounds__(256) void k4_out(
    const float* __restrict__ x1p, const float* __restrict__ supp,
    const float* __restrict__ ww, const float* __restrict__ wb,
    float* __restrict__ out)
{
  const int tid = threadIdx.x;
  const int b = blockIdx.x >> 6;
  const int n0 = (blockIdx.x & 63) << 6;

  __shared__ float x1L[64 * 33];
  __shared__ float wwL[64 * 33];

  for (int e = tid; e < C_ * CI_; e += 256)
    wwL[(e >> 5) * 33 + (e & 31)] = ww[e];
  for (int e = tid; e < 64 * 32; e += 256) {
    int n = e >> 5, i = e & 31;
    size_t base = (((size_t)b * 2 * N_) + n0 + n) * 32 + i;
    x1L[n * 33 + i] = x1p[base] + x1p[base + (size_t)N_ * 32];
  }
  __syncthreads();

  const int nq = tid & 15;
  const int c0 = tid >> 4;
#pragma unroll
  for (int k = 0; k < 4; k++) {
    int c = c0 + k * 16;
    float bv = wb[c];
    float a0 = bv, a1 = bv, a2 = bv, a3 = bv;
    const float* xr = &x1L[nq * 4 * 33];
#pragma unroll 8
    for (int i = 0; i < CI_; i++) {
      float wv = wwL[c * 33 + i];
      a0 = fmaf(wv, xr[i], a0);
      a1 = fmaf(wv, xr[33 + i], a1);
      a2 = fmaf(wv, xr[66 + i], a2);
      a3 = fmaf(wv, xr[99 + i], a3);
    }
    size_t ob = ((size_t)b * C_ + c) * N_ + n0 + nq * 4;
    float4 s = *(const float4*)(supp + ob);
    float4 o;
    o.x = a0 + s.x; o.y = a1 + s.y; o.z = a2 + s.z; o.w = a3 + s.w;
    *(float4*)(out + ob) = o;
  }
}

extern "C" void kernel_launch(void* const* d_in, const int* in_sizes, int n_in,
                              void* d_out, int out_size, void* d_ws, size_t ws_size,
                              hipStream_t stream)
{
  const float* supp = (const float*)d_in[0];
  const float* ref  = (const float*)d_in[1];
  const float* tw   = (const float*)d_in[2];
  const float* tb   = (const float*)d_in[3];
  const float* pw   = (const float*)d_in[4];
  const float* pb   = (const float*)d_in[5];
  const float* gw   = (const float*)d_in[6];
  const float* gb   = (const float*)d_in[7];
  const float* ww   = (const float*)d_in[8];
  const float* wb   = (const float*)d_in[9];
  float* out = (float*)d_out;

  char* ws = (char*)d_ws;
  unsigned short* theta = (unsigned short*)ws;                   // 1 MB
  unsigned short* phi   = (unsigned short*)(ws + (1u << 20));    // 1 MB
  float*          gt    = (float*)(ws + (2u << 20));             // 2 MB
  unsigned short* gy2i  = (unsigned short*)(ws + (4u << 20));    // 1 MB
  float*          x1p   = (float*)(ws + (5u << 20));             // 4 MB

  hipLaunchKernelGGL(k1_proj, dim3(192), dim3(256), 0, stream,
                     supp, ref, tw, tb, pw, pb, gw, gb, theta, phi, gt);
  hipLaunchKernelGGL(k2_den, dim3(256), dim3(1024), 0, stream,
                     theta, phi, gt, gy2i);
  hipLaunchKernelGGL(k3_attn, dim3(256), dim3(512), 0, stream,
                     theta, phi, gy2i, x1p);
  hipLaunchKernelGGL(k4_out, dim3(256), dim3(256), 0, stream,
                     x1p, supp, ww, wb, out);
}

// Round 5
// 144.401 us; speedup vs baseline: 1.0416x; 1.0416x over previous
//
#include <hip/hip_runtime.h>

#define C_ 64
#define CI_ 32
#define N_ 4096
#define LOG2E 1.4426950408889634f

typedef __attribute__((ext_vector_type(8))) short bf16x8;
typedef __attribute__((ext_vector_type(4))) float f32x4;

__device__ __forceinline__ unsigned short f2bf_rne(float f) {
  unsigned u = __builtin_bit_cast(unsigned, f);
  unsigned r = (u + 0x7FFFu + ((u >> 16) & 1u)) >> 16;
  return (unsigned short)r;
}
__device__ __forceinline__ unsigned pack_bf2(float lo, float hi) {
  unsigned a = (__builtin_bit_cast(unsigned, lo) + 0x8000u) >> 16;
  unsigned b = (__builtin_bit_cast(unsigned, hi) + 0x8000u) & 0xFFFF0000u;
  return a | b;
}

// ---------------------------------------------------------------------------
// K1: projections. Grid 768 = (proj x b x 64 n-tiles of 64). 256 thr; wave =
// channel octet, lane = one n. theta pre-scaled by log2(e).
// ---------------------------------------------------------------------------
__global__ __launch_bounds__(256) void k1_proj(
    const float* __restrict__ supp, const float* __restrict__ ref,
    const float* __restrict__ tw, const float* __restrict__ tb,
    const float* __restrict__ pw, const float* __restrict__ pb,
    const float* __restrict__ gw, const float* __restrict__ gb,
    unsigned short* __restrict__ theta, unsigned short* __restrict__ phi,
    float* __restrict__ gt)
{
  const int proj = blockIdx.x >> 8;
  const int rr = blockIdx.x & 255;
  const int b = rr >> 6;
  const int n0 = (rr & 63) << 6;
  const int o = __builtin_amdgcn_readfirstlane(threadIdx.x >> 6);
  const int lane = threadIdx.x & 63;
  const int n = n0 + lane;

  const float *W, *bias, *src;
  if (proj == 0)      { W = tw; bias = tb; src = supp; }
  else if (proj == 1) { W = pw; bias = pb; src = ref; }
  else                { W = gw; bias = gb; src = ref; }

  const float* x = src + (size_t)b * (C_ * N_) + n;
  const float* Wo = W + o * 8 * C_;
  float acc[8];
#pragma unroll
  for (int k = 0; k < 8; k++) acc[k] = bias[o * 8 + k];
#pragma unroll 8
  for (int c = 0; c < C_; c++) {
    float v = x[(size_t)c * N_];
#pragma unroll
    for (int k = 0; k < 8; k++) acc[k] = fmaf(Wo[k * C_ + c], v, acc[k]);
  }

  const size_t p = (size_t)b * N_ + n;
  if (proj == 0) {
    unsigned pk[4];
#pragma unroll
    for (int k = 0; k < 4; k++)
      pk[k] = (unsigned)f2bf_rne(acc[2 * k] * LOG2E) |
              ((unsigned)f2bf_rne(acc[2 * k + 1] * LOG2E) << 16);
    *(uint4*)(theta + (p << 5) + o * 8) = *(uint4*)pk;
  } else if (proj == 1) {
    unsigned pk[4];
#pragma unroll
    for (int k = 0; k < 4; k++)
      pk[k] = (unsigned)f2bf_rne(acc[2 * k]) |
              ((unsigned)f2bf_rne(acc[2 * k + 1]) << 16);
    *(uint4*)(phi + (p << 5) + o * 8) = *(uint4*)pk;
  } else {
    float* dst = gt + ((size_t)b * CI_ + o * 8) * N_ + n;
#pragma unroll
    for (int k = 0; k < 8; k++) dst[(size_t)k * N_] = acc[k];
  }
}

// ---------------------------------------------------------------------------
// K2: den[m] = sum_n exp2(f'); gy2i[b][i][mbase + p] = bf16(gt[sig(p)]/den).
// Grid 256 = (b x 64 m-tiles of 64). 16 waves = 256-n slices; 4 persistent
// phi B-frags; depth-2 theta prefetch.
// sigma (per 32-chunk): p = 8q+j -> m = 4q + (j&3) + 16*(j>>2)  — matches the
// lane-local P packing in K3 so the PV k-reduction stays aligned.
// ---------------------------------------------------------------------------
__global__ __launch_bounds__(1024) void k2_den(
    const unsigned short* __restrict__ theta, const unsigned short* __restrict__ phi,
    const float* __restrict__ gt, unsigned short* __restrict__ gy2i)
{
  const int tid = threadIdx.x;
  const int wave = tid >> 6;
  const int lane = tid & 63;
  const int b = blockIdx.x >> 6;
  const int mbase = (blockIdx.x & 63) << 6;
  const int row16 = lane & 15;
  const int quad = lane >> 4;

  bf16x8 bf[4];
#pragma unroll
  for (int f = 0; f < 4; f++)
    bf[f] = *(const bf16x8*)(phi +
        (((size_t)b * N_ + mbase + f * 16 + row16) << 5) + (quad << 3));

  const unsigned short* abase = theta +
      (((size_t)b * N_ + wave * 256 + row16) << 5) + (quad << 3);

  f32x4 zero = {0.f, 0.f, 0.f, 0.f};
  float dd[16];
#pragma unroll
  for (int k = 0; k < 16; k++) dd[k] = 0.f;

  bf16x8 a0 = *(const bf16x8*)abase;
  bf16x8 a1 = *(const bf16x8*)(abase + 512);
#pragma unroll 2
  for (int it = 0; it < 16; it++) {
    int itn = it + 2 <= 15 ? it + 2 : 15;
    bf16x8 an = *(const bf16x8*)(abase + ((size_t)itn << 9));
#pragma unroll
    for (int f = 0; f < 4; f++) {
      f32x4 ff = __builtin_amdgcn_mfma_f32_16x16x32_bf16(a0, bf[f], zero, 0, 0, 0);
#pragma unroll
      for (int r = 0; r < 4; r++) dd[f * 4 + r] += __builtin_amdgcn_exp2f(ff[r]);
    }
    a0 = a1; a1 = an;
  }

  __shared__ float denp[16][64];
#pragma unroll
  for (int f = 0; f < 4; f++) {
    float v = (dd[f * 4] + dd[f * 4 + 1]) + (dd[f * 4 + 2] + dd[f * 4 + 3]);
    v += __shfl_xor(v, 16);
    v += __shfl_xor(v, 32);
    if (lane < 16) denp[wave][f * 16 + lane] = v;
  }
  __syncthreads();

  for (int e = tid; e < CI_ * 64; e += 1024) {
    int i = e >> 6;
    int p = e & 63;
    int pw = p & 31;
    int ml = (p & 32) + ((pw >> 3) << 2) + (pw & 3) + (((pw >> 2) & 1) << 4);
    float den = 0.f;
#pragma unroll
    for (int w = 0; w < 16; w++) den += denp[w][ml];
    size_t rowb = ((size_t)b * CI_ + i) * N_ + mbase;
    gy2i[rowb + p] = f2bf_rne(gt[rowb + ml] / den);
  }
}

// ---------------------------------------------------------------------------
// K3: x1[i,n] partial over an m-quarter — ZERO LDS. Grid 512 = (b x 32
// n-tiles of 128 x 4 m-quarters); 8 waves, one 16-n subtile each (16 wv/CU).
// fT = mfma(A=phi[m rows], B=theta[n cols]) -> D[m][n]; lane (n+16q) holds
// m in {4q..4q+3, 16+4q..+3} — exactly the PV B-operand's k = 8q+j slots
// under sigma. So P->PV is 4 lane-local packs; PV: A=gy2i (sigma-stored),
// B=packed P, D[i][n]. Depth-2 prefetch on phi and gy2 streams.
// ---------------------------------------------------------------------------
__global__ __launch_bounds__(512, 4) void k3_attn(
    const unsigned short* __restrict__ theta, const unsigned short* __restrict__ phi,
    const unsigned short* __restrict__ gy2i, unsigned short* __restrict__ x1p)
{
  const int tid = threadIdx.x;
  const int w = tid >> 6;
  const int lane = tid & 63;
  const int b = blockIdx.x >> 7;
  const int r2 = blockIdx.x & 127;
  const int nt = r2 >> 2;
  const int mq = r2 & 3;
  const int row16 = lane & 15;
  const int quad = lane >> 4;

  bf16x8 tB = *(const bf16x8*)(theta +
      (((size_t)b * N_ + nt * 128 + w * 16 + row16) << 5) + (quad << 3));

  const unsigned short* pp = phi +
      (((size_t)b * N_ + mq * 1024 + row16) << 5) + (quad << 3);
  const unsigned short* gp = gy2i +
      ((size_t)b * CI_ + row16) * N_ + mq * 1024 + (quad << 3);

  f32x4 zero = {0.f, 0.f, 0.f, 0.f};
  f32x4 xa = zero, xb = zero;

  bf16x8 p0c = *(const bf16x8*)pp;
  bf16x8 p1c = *(const bf16x8*)(pp + 512);
  bf16x8 g0c = *(const bf16x8*)gp;
  bf16x8 g1c = *(const bf16x8*)(gp + (size_t)16 * N_);
  bf16x8 p0n = *(const bf16x8*)(pp + 1024);
  bf16x8 p1n = *(const bf16x8*)(pp + 1536);
  bf16x8 g0n = *(const bf16x8*)(gp + 32);
  bf16x8 g1n = *(const bf16x8*)(gp + (size_t)16 * N_ + 32);

  for (int it = 0; it < 32; it++) {
    f32x4 f0 = __builtin_amdgcn_mfma_f32_16x16x32_bf16(p0c, tB, zero, 0, 0, 0);
    f32x4 f1 = __builtin_amdgcn_mfma_f32_16x16x32_bf16(p1c, tB, zero, 0, 0, 0);
    int itf = it + 2 <= 31 ? it + 2 : 31;
    bf16x8 p0f = *(const bf16x8*)(pp + itf * 1024);
    bf16x8 p1f = *(const bf16x8*)(pp + itf * 1024 + 512);
    bf16x8 g0f = *(const bf16x8*)(gp + itf * 32);
    bf16x8 g1f = *(const bf16x8*)(gp + (size_t)16 * N_ + itf * 32);

    uint4 dd;
    dd.x = pack_bf2(__builtin_amdgcn_exp2f(f0[0]), __builtin_amdgcn_exp2f(f0[1]));
    dd.y = pack_bf2(__builtin_amdgcn_exp2f(f0[2]), __builtin_amdgcn_exp2f(f0[3]));
    dd.z = pack_bf2(__builtin_amdgcn_exp2f(f1[0]), __builtin_amdgcn_exp2f(f1[1]));
    dd.w = pack_bf2(__builtin_amdgcn_exp2f(f1[2]), __builtin_amdgcn_exp2f(f1[3]));
    bf16x8 Pb = __builtin_bit_cast(bf16x8, dd);

    xa = __builtin_amdgcn_mfma_f32_16x16x32_bf16(g0c, Pb, xa, 0, 0, 0);
    xb = __builtin_amdgcn_mfma_f32_16x16x32_bf16(g1c, Pb, xb, 0, 0, 0);

    p0c = p0n; p0n = p0f;
    p1c = p1n; p1n = p1f;
    g0c = g0n; g0n = g0f;
    g1c = g1n; g1n = g1f;
  }

  // D[i][n]: i = quad*4+r (+16 for xb), n = nt*128 + w*16 + row16
  const int nglob = nt * 128 + w * 16 + row16;
  size_t base = (((size_t)(b * 4 + mq) * CI_) + quad * 4) * N_ + nglob;
#pragma unroll
  for (int r = 0; r < 4; r++) {
    x1p[base + (size_t)r * N_] = f2bf_rne(xa[r]);
    x1p[base + (size_t)(16 + r) * N_] = f2bf_rne(xb[r]);
  }
}

// ---------------------------------------------------------------------------
// K4: x1 = sum of 4 m-quarter partials (bf16); out = supp + ww.x1 + wb.
// Grid 512 = (b x 128 n-tiles of 32). 256 thr; thread = (c, 8 n).
// ---------------------------------------------------------------------------
__global__ __launch_bounds__(256) void k4_out(
    const unsigned short* __restrict__ x1p, const float* __restrict__ supp,
    const float* __restrict__ ww, const float* __restrict__ wb,
    float* __restrict__ out)
{
  const int tid = threadIdx.x;
  const int b = blockIdx.x >> 7;
  const int n0 = (blockIdx.x & 127) << 5;

  __shared__ float x1L[CI_ * 33];
  __shared__ float wwL[C_ * 33];

  for (int e = tid; e < C_ * CI_; e += 256)
    wwL[(e >> 5) * 33 + (e & 31)] = ww[e];
  for (int e = tid; e < CI_ * 32; e += 256) {
    int i = e >> 5, nl = e & 31;
    size_t a = ((size_t)b * 4 * CI_ + i) * N_ + n0 + nl;
    unsigned s0 = x1p[a];
    unsigned s1 = x1p[a + (size_t)CI_ * N_];
    unsigned s2 = x1p[a + (size_t)2 * CI_ * N_];
    unsigned s3 = x1p[a + (size_t)3 * CI_ * N_];
    x1L[i * 33 + nl] =
        (__builtin_bit_cast(float, s0 << 16) + __builtin_bit_cast(float, s1 << 16)) +
        (__builtin_bit_cast(float, s2 << 16) + __builtin_bit_cast(float, s3 << 16));
  }
  __syncthreads();

  const int c = tid >> 2;
  const int nl0 = (tid & 3) << 3;
  float a[8];
  float bv = wb[c];
#pragma unroll
  for (int j = 0; j < 8; j++) a[j] = bv;
#pragma unroll 8
  for (int i = 0; i < CI_; i++) {
    float wv = wwL[c * 33 + i];
    const float* xr = &x1L[i * 33 + nl0];
#pragma unroll
    for (int j = 0; j < 8; j++) a[j] = fmaf(wv, xr[j], a[j]);
  }
  size_t ob = ((size_t)b * C_ + c) * N_ + n0 + nl0;
  float4 s0 = *(const float4*)(supp + ob);
  float4 s1 = *(const float4*)(supp + ob + 4);
  float4 o0, o1;
  o0.x = a[0] + s0.x; o0.y = a[1] + s0.y; o0.z = a[2] + s0.z; o0.w = a[3] + s0.w;
  o1.x = a[4] + s1.x; o1.y = a[5] + s1.y; o1.z = a[6] + s1.z; o1.w = a[7] + s1.w;
  *(float4*)(out + ob) = o0;
  *(float4*)(out + ob + 4) = o1;
}

extern "C" void kernel_launch(void* const* d_in, const int* in_sizes, int n_in,
                              void* d_out, int out_size, void* d_ws, size_t ws_size,
                              hipStream_t stream)
{
  const float* supp = (const float*)d_in[0];
  const float* ref  = (const float*)d_in[1];
  const float* tw   = (const float*)d_in[2];
  const float* tb   = (const float*)d_in[3];
  const float* pw   = (const float*)d_in[4];
  const float* pb   = (const float*)d_in[5];
  const float* gw   = (const float*)d_in[6];
  const float* gb   = (const float*)d_in[7];
  const float* ww   = (const float*)d_in[8];
  const float* wb   = (const float*)d_in[9];
  float* out = (float*)d_out;

  char* ws = (char*)d_ws;
  unsigned short* theta = (unsigned short*)ws;                   // 1 MB
  unsigned short* phi   = (unsigned short*)(ws + (1u << 20));    // 1 MB
  float*          gt    = (float*)(ws + (2u << 20));             // 2 MB
  unsigned short* gy2i  = (unsigned short*)(ws + (4u << 20));    // 1 MB
  unsigned short* x1p   = (unsigned short*)(ws + (5u << 20));    // 4 MB (bf16)

  hipLaunchKernelGGL(k1_proj, dim3(768), dim3(256), 0, stream,
                     supp, ref, tw, tb, pw, pb, gw, gb, theta, phi, gt);
  hipLaunchKernelGGL(k2_den, dim3(256), dim3(1024), 0, stream,
                     theta, phi, gt, gy2i);
  hipLaunchKernelGGL(k3_attn, dim3(512), dim3(512), 0, stream,
                     theta, phi, gy2i, x1p);
  hipLaunchKernelGGL(k4_out, dim3(512), dim3(256), 0, stream,
                     x1p, supp, ww, wb, out);
}

// Round 6
// 118.409 us; speedup vs baseline: 1.2703x; 1.2195x over previous
//
#include <hip/hip_runtime.h>

#define C_ 64
#define CI_ 32
#define N_ 4096
#define LOG2E 1.4426950408889634f

typedef __attribute__((ext_vector_type(8))) short bf16x8;
typedef __attribute__((ext_vector_type(4))) float f32x4;

__device__ __forceinline__ unsigned short f2bf_rne(float f) {
  unsigned u = __builtin_bit_cast(unsigned, f);
  unsigned r = (u + 0x7FFFu + ((u >> 16) & 1u)) >> 16;
  return (unsigned short)r;
}
__device__ __forceinline__ unsigned pack_bf2(float lo, float hi) {
  unsigned a = (__builtin_bit_cast(unsigned, lo) + 0x8000u) >> 16;
  unsigned b = (__builtin_bit_cast(unsigned, hi) + 0x8000u) & 0xFFFF0000u;
  return a | b;
}
__device__ __forceinline__ float bf2f(unsigned short v) {
  return __builtin_bit_cast(float, (unsigned)v << 16);
}
// async DMA global->LDS, 16B/lane, LDS dst = uniform base + lane*16
__device__ __forceinline__ void dma16(const void* gp, const void* lp) {
  __builtin_amdgcn_global_load_lds(
      (const __attribute__((address_space(1))) unsigned*)(unsigned long long)gp,
      (__attribute__((address_space(3))) unsigned*)(unsigned)(unsigned long long)lp,
      16, 0, 0);
}

// sigma (per 32-m chunk): slot p=8q+j -> m_local = 4q + (j&3) + 16*(j>>2).
// Chunked k-major layouts (2KB per chunk, DMA-contiguous, conflict-free ds_read):
//   phi2[b][ch][q][r=m_local][j]   (k = channel 8q+j)
//   g2  [b][ch][q][i][j]           (k = sigma-slot p=8q+j, value g[i][ch*32+sigma(p)])
//   rden[b][ch][p] = 1/den[ch*32+sigma(p)]

// ---------------------------------------------------------------------------
// K1: projections. Grid 768 = (proj x b x 64 n-tiles of 64). 256 thr; wave =
// channel octet o, lane = one position. theta pre-scaled by log2(e).
// ---------------------------------------------------------------------------
__global__ __launch_bounds__(256) void k1_proj(
    const float* __restrict__ supp, const float* __restrict__ ref,
    const float* __restrict__ tw, const float* __restrict__ tb,
    const float* __restrict__ pw, const float* __restrict__ pb,
    const float* __restrict__ gw, const float* __restrict__ gb,
    unsigned short* __restrict__ theta, unsigned short* __restrict__ phi2,
    unsigned short* __restrict__ g2)
{
  const int proj = blockIdx.x >> 8;
  const int rr = blockIdx.x & 255;
  const int b = rr >> 6;
  const int n0 = (rr & 63) << 6;
  const int o = __builtin_amdgcn_readfirstlane(threadIdx.x >> 6);
  const int lane = threadIdx.x & 63;
  const int n = n0 + lane;

  const float *W, *bias, *src;
  if (proj == 0)      { W = tw; bias = tb; src = supp; }
  else if (proj == 1) { W = pw; bias = pb; src = ref; }
  else                { W = gw; bias = gb; src = ref; }

  const float* x = src + (size_t)b * (C_ * N_) + n;
  const float* Wo = W + o * 8 * C_;
  float acc[8];
#pragma unroll
  for (int k = 0; k < 8; k++) acc[k] = bias[o * 8 + k];
#pragma unroll 8
  for (int c = 0; c < C_; c++) {
    float v = x[(size_t)c * N_];
#pragma unroll
    for (int k = 0; k < 8; k++) acc[k] = fmaf(Wo[k * C_ + c], v, acc[k]);
  }

  if (proj == 0) {
    unsigned pk[4];
#pragma unroll
    for (int k = 0; k < 4; k++)
      pk[k] = (unsigned)f2bf_rne(acc[2 * k] * LOG2E) |
              ((unsigned)f2bf_rne(acc[2 * k + 1] * LOG2E) << 16);
    *(uint4*)(theta + (((size_t)b * N_ + n) << 5) + o * 8) = *(uint4*)pk;
  } else if (proj == 1) {
    // phi2: [b][ch=n>>5][q=o][r=n&31][j]
    unsigned pk[4];
#pragma unroll
    for (int k = 0; k < 4; k++)
      pk[k] = (unsigned)f2bf_rne(acc[2 * k]) |
              ((unsigned)f2bf_rne(acc[2 * k + 1]) << 16);
    size_t off = (((size_t)b * 128 + (n >> 5)) << 10) + o * 256 + (n & 31) * 8;
    *(uint4*)(phi2 + off) = *(uint4*)pk;
  } else {
    // g2: thread's m=n fixes (q,j) via sigma-inverse; channels i=8o..8o+7
    int ml = n & 31;
    int q = (ml & 15) >> 2;
    int j = (ml & 3) | (((ml >> 4) & 1) << 2);
    size_t base = (((size_t)b * 128 + (n >> 5)) << 10) + q * 256 + j;
#pragma unroll
    for (int t = 0; t < 8; t++)
      g2[base + (8 * o + t) * 8] = f2bf_rne(acc[t]);
  }
}

// ---------------------------------------------------------------------------
// K2: den[m] = sum_n exp2(f'); writes rden only (sigma-ordered reciprocals).
// Grid 256 = (b x 64 m-tiles of 64). 16 waves = 256-n slices; 4 persistent
// phi B-frags (from chunked phi2); depth-2 theta prefetch.
// ---------------------------------------------------------------------------
__global__ __launch_bounds__(1024) void k2_den(
    const unsigned short* __restrict__ theta, const unsigned short* __restrict__ phi2,
    float* __restrict__ rden)
{
  const int tid = threadIdx.x;
  const int wave = tid >> 6;
  const int lane = tid & 63;
  const int b = blockIdx.x >> 6;
  const int mbase = (blockIdx.x & 63) << 6;
  const int row16 = lane & 15;
  const int quad = lane >> 4;

  bf16x8 bf[4];
#pragma unroll
  for (int f = 0; f < 4; f++) {
    int ch = (mbase >> 5) + (f >> 1);
    int r = ((f & 1) << 4) + row16;
    bf[f] = *(const bf16x8*)(phi2 +
        (((size_t)b * 128 + ch) << 10) + (quad << 8) + r * 8);
  }

  const unsigned short* abase = theta +
      (((size_t)b * N_ + wave * 256 + row16) << 5) + (quad << 3);

  f32x4 zero = {0.f, 0.f, 0.f, 0.f};
  float dd[16];
#pragma unroll
  for (int k = 0; k < 16; k++) dd[k] = 0.f;

  bf16x8 a0 = *(const bf16x8*)abase;
  bf16x8 a1 = *(const bf16x8*)(abase + 512);
#pragma unroll 2
  for (int it = 0; it < 16; it++) {
    int itn = it + 2 <= 15 ? it + 2 : 15;
    bf16x8 an = *(const bf16x8*)(abase + ((size_t)itn << 9));
#pragma unroll
    for (int f = 0; f < 4; f++) {
      f32x4 ff = __builtin_amdgcn_mfma_f32_16x16x32_bf16(a0, bf[f], zero, 0, 0, 0);
#pragma unroll
      for (int r = 0; r < 4; r++) dd[f * 4 + r] += __builtin_amdgcn_exp2f(ff[r]);
    }
    a0 = a1; a1 = an;
  }

  __shared__ float denp[16][64];
#pragma unroll
  for (int f = 0; f < 4; f++) {
    float v = (dd[f * 4] + dd[f * 4 + 1]) + (dd[f * 4 + 2] + dd[f * 4 + 3]);
    v += __shfl_xor(v, 16);
    v += __shfl_xor(v, 32);
    if (lane < 16) denp[wave][f * 16 + lane] = v;
  }
  __syncthreads();

  if (tid < 64) {
    int p = tid;
    int q = (p >> 3) & 3, j = p & 7;
    int ml = (p & 32) + 4 * q + (j & 3) + ((j >> 2) << 4);
    float den = 0.f;
#pragma unroll
    for (int w = 0; w < 16; w++) den += denp[w][ml];
    rden[(((size_t)b * 128 + (mbase >> 5) + (p >> 5)) << 5) + (p & 31)] = 1.0f / den;
  }
}

// ---------------------------------------------------------------------------
// K3: x1[i,n] partial over an m-eighth (512 m = 16 chunks of 32).
// Grid 512 = (b x 16 n-tiles of 256 x 8 m-eighths); 8 waves x 32 n each;
// 2 blocks/CU. Phases of 4 chunks: DMA-stage phi2+g2 chunks into 16KB LDS
// (global_load_lds, nothing for the compiler to sink), barrier, compute.
// P = exp2(fT)*rden packed lane-locally (sigma), PV accumulates D[i][n].
// ---------------------------------------------------------------------------
__global__ __launch_bounds__(512, 2) void k3_attn(
    const unsigned short* __restrict__ theta, const unsigned short* __restrict__ phi2,
    const unsigned short* __restrict__ g2, const float* __restrict__ rden,
    unsigned short* __restrict__ x1p)
{
  const int tid = threadIdx.x;
  const int w = tid >> 6;
  const int lane = tid & 63;
  const int b = blockIdx.x >> 7;
  const int nt = (blockIdx.x >> 3) & 15;
  const int ms = blockIdx.x & 7;
  const int row16 = lane & 15;
  const int quad = lane >> 4;

  __shared__ __align__(16) unsigned short SB[4 * 2048];  // 16 KB: [chunk][phi|g][1024]

  const int nbase = nt * 256 + w * 32;
  bf16x8 tB0 = *(const bf16x8*)(theta + (((size_t)b * N_ + nbase + row16) << 5) + (quad << 3));
  bf16x8 tB1 = *(const bf16x8*)(theta + (((size_t)b * N_ + nbase + 16 + row16) << 5) + (quad << 3));

  const size_t chunkb = (size_t)b * 128 + ms * 16;

  f32x4 zero = {0.f, 0.f, 0.f, 0.f};
  f32x4 xa0 = zero, xb0 = zero, xa1 = zero, xb1 = zero;

  for (int ph = 0; ph < 4; ph++) {
    // stage phase: 4 chunks x (phi,g) x 2 halves = 16 x 1KB; 2 per wave
#pragma unroll
    for (int s = 0; s < 2; s++) {
      int idx = w * 2 + s;
      int c = idx >> 2;
      int a = (idx >> 1) & 1;
      int h = idx & 1;
      const unsigned short* src = (a ? g2 : phi2) +
          ((chunkb + ph * 4 + c) << 10) + (h << 9) + lane * 8;
      const unsigned short* dst = SB + c * 2048 + a * 1024 + h * 512;
      dma16(src, dst);
    }
    __syncthreads();
#pragma unroll
    for (int c = 0; c < 4; c++) {
      const unsigned short* lphi = SB + c * 2048;
      const unsigned short* lg = SB + c * 2048 + 1024;
      bf16x8 pA0 = *(const bf16x8*)(lphi + (quad << 8) + row16 * 8);
      bf16x8 pA1 = *(const bf16x8*)(lphi + (quad << 8) + (row16 + 16) * 8);
      bf16x8 gA0 = *(const bf16x8*)(lg + (quad << 8) + row16 * 8);
      bf16x8 gA1 = *(const bf16x8*)(lg + (quad << 8) + (row16 + 16) * 8);
      const float* rp = rden + ((chunkb + ph * 4 + c) << 5) + (quad << 3);
      f32x4 r0 = *(const f32x4*)rp;
      f32x4 r1 = *(const f32x4*)(rp + 4);

      f32x4 f00 = __builtin_amdgcn_mfma_f32_16x16x32_bf16(pA0, tB0, zero, 0, 0, 0);
      f32x4 f10 = __builtin_amdgcn_mfma_f32_16x16x32_bf16(pA1, tB0, zero, 0, 0, 0);
      f32x4 f01 = __builtin_amdgcn_mfma_f32_16x16x32_bf16(pA0, tB1, zero, 0, 0, 0);
      f32x4 f11 = __builtin_amdgcn_mfma_f32_16x16x32_bf16(pA1, tB1, zero, 0, 0, 0);

      uint4 d0, d1;
      d0.x = pack_bf2(__builtin_amdgcn_exp2f(f00[0]) * r0[0],
                      __builtin_amdgcn_exp2f(f00[1]) * r0[1]);
      d0.y = pack_bf2(__builtin_amdgcn_exp2f(f00[2]) * r0[2],
                      __builtin_amdgcn_exp2f(f00[3]) * r0[3]);
      d0.z = pack_bf2(__builtin_amdgcn_exp2f(f10[0]) * r1[0],
                      __builtin_amdgcn_exp2f(f10[1]) * r1[1]);
      d0.w = pack_bf2(__builtin_amdgcn_exp2f(f10[2]) * r1[2],
                      __builtin_amdgcn_exp2f(f10[3]) * r1[3]);
      d1.x = pack_bf2(__builtin_amdgcn_exp2f(f01[0]) * r0[0],
                      __builtin_amdgcn_exp2f(f01[1]) * r0[1]);
      d1.y = pack_bf2(__builtin_amdgcn_exp2f(f01[2]) * r0[2],
                      __builtin_amdgcn_exp2f(f01[3]) * r0[3]);
      d1.z = pack_bf2(__builtin_amdgcn_exp2f(f11[0]) * r1[0],
                      __builtin_amdgcn_exp2f(f11[1]) * r1[1]);
      d1.w = pack_bf2(__builtin_amdgcn_exp2f(f11[2]) * r1[2],
                      __builtin_amdgcn_exp2f(f11[3]) * r1[3]);
      bf16x8 Pb0 = __builtin_bit_cast(bf16x8, d0);
      bf16x8 Pb1 = __builtin_bit_cast(bf16x8, d1);

      xa0 = __builtin_amdgcn_mfma_f32_16x16x32_bf16(gA0, Pb0, xa0, 0, 0, 0);
      xb0 = __builtin_amdgcn_mfma_f32_16x16x32_bf16(gA1, Pb0, xb0, 0, 0, 0);
      xa1 = __builtin_amdgcn_mfma_f32_16x16x32_bf16(gA0, Pb1, xa1, 0, 0, 0);
      xb1 = __builtin_amdgcn_mfma_f32_16x16x32_bf16(gA1, Pb1, xb1, 0, 0, 0);
    }
    __syncthreads();
  }

  // writeout: x1p[b*8+ms][i][n]; i = quad*4+r (+16 for xb), n = nbase + j*16 + row16
  size_t obase = ((size_t)(b * 8 + ms) * CI_) * N_;
#pragma unroll
  for (int r = 0; r < 4; r++) {
    size_t i0 = (size_t)(quad * 4 + r) * N_;
    size_t i1 = (size_t)(16 + quad * 4 + r) * N_;
    x1p[obase + i0 + nbase + row16] = f2bf_rne(xa0[r]);
    x1p[obase + i0 + nbase + 16 + row16] = f2bf_rne(xa1[r]);
    x1p[obase + i1 + nbase + row16] = f2bf_rne(xb0[r]);
    x1p[obase + i1 + nbase + 16 + row16] = f2bf_rne(xb1[r]);
  }
}

// ---------------------------------------------------------------------------
// K4: x1 = sum of 8 m-eighth partials (bf16); out = supp + ww.x1 + wb.
// Grid 512 = (b x 128 n-tiles of 32). 256 thr.
// ---------------------------------------------------------------------------
__global__ __launch_bounds__(256) void k4_out(
    const unsigned short* __restrict__ x1p, const float* __restrict__ supp,
    const float* __restrict__ ww, const float* __restrict__ wb,
    float* __restrict__ out)
{
  const int tid = threadIdx.x;
  const int b = blockIdx.x >> 7;
  const int n0 = (blockIdx.x & 127) << 5;

  __shared__ float x1L[CI_ * 33];
  __shared__ float wwL[C_ * 33];

  for (int e = tid; e < C_ * CI_; e += 256)
    wwL[(e >> 5) * 33 + (e & 31)] = ww[e];
  for (int e = tid; e < CI_ * 32; e += 256) {
    int i = e >> 5, nl = e & 31;
    size_t a = ((size_t)b * 8 * CI_ + i) * N_ + n0 + nl;
    float s = 0.f;
#pragma unroll
    for (int q = 0; q < 8; q++) s += bf2f(x1p[a + (size_t)q * CI_ * N_]);
    x1L[i * 33 + nl] = s;
  }
  __syncthreads();

  const int c = tid >> 2;
  const int nl0 = (tid & 3) << 3;
  float a[8];
  float bv = wb[c];
#pragma unroll
  for (int j = 0; j < 8; j++) a[j] = bv;
#pragma unroll 8
  for (int i = 0; i < CI_; i++) {
    float wv = wwL[c * 33 + i];
    const float* xr = &x1L[i * 33 + nl0];
#pragma unroll
    for (int j = 0; j < 8; j++) a[j] = fmaf(wv, xr[j], a[j]);
  }
  size_t ob = ((size_t)b * C_ + c) * N_ + n0 + nl0;
  float4 s0 = *(const float4*)(supp + ob);
  float4 s1 = *(const float4*)(supp + ob + 4);
  float4 o0, o1;
  o0.x = a[0] + s0.x; o0.y = a[1] + s0.y; o0.z = a[2] + s0.z; o0.w = a[3] + s0.w;
  o1.x = a[4] + s1.x; o1.y = a[5] + s1.y; o1.z = a[6] + s1.z; o1.w = a[7] + s1.w;
  *(float4*)(out + ob) = o0;
  *(float4*)(out + ob + 4) = o1;
}

extern "C" void kernel_launch(void* const* d_in, const int* in_sizes, int n_in,
                              void* d_out, int out_size, void* d_ws, size_t ws_size,
                              hipStream_t stream)
{
  const float* supp = (const float*)d_in[0];
  const float* ref  = (const float*)d_in[1];
  const float* tw   = (const float*)d_in[2];
  const float* tb   = (const float*)d_in[3];
  const float* pw   = (const float*)d_in[4];
  const float* pb   = (const float*)d_in[5];
  const float* gw   = (const float*)d_in[6];
  const float* gb   = (const float*)d_in[7];
  const float* ww   = (const float*)d_in[8];
  const float* wb   = (const float*)d_in[9];
  float* out = (float*)d_out;

  char* ws = (char*)d_ws;
  unsigned short* theta = (unsigned short*)ws;                   // 1 MB
  unsigned short* phi2  = (unsigned short*)(ws + (1u << 20));    // 1 MB (chunked)
  unsigned short* g2    = (unsigned short*)(ws + (2u << 20));    // 1 MB (chunked, sigma)
  float*          rden  = (float*)(ws + (3u << 20));             // 64 KB
  unsigned short* x1p   = (unsigned short*)(ws + (4u << 20));    // 8 MB (bf16)

  hipLaunchKernelGGL(k1_proj, dim3(768), dim3(256), 0, stream,
                     supp, ref, tw, tb, pw, pb, gw, gb, theta, phi2, g2);
  hipLaunchKernelGGL(k2_den, dim3(256), dim3(1024), 0, stream,
                     theta, phi2, rden);
  hipLaunchKernelGGL(k3_attn, dim3(512), dim3(512), 0, stream,
                     theta, phi2, g2, rden, x1p);
  hipLaunchKernelGGL(k4_out, dim3(512), dim3(256), 0, stream,
                     x1p, supp, ww, wb, out);
}